// Round 15
// baseline (691.935 us; speedup 1.0000x reference)
//
#include <hip/hip_runtime.h>
#include <hip/hip_bf16.h>

#define Nn 20000
#define EREL 60000
#define ETOT 180000
#define NG 64
#define FD 384
#define EPS 1e-5f

typedef unsigned short u16;
typedef unsigned int u32;
typedef __attribute__((ext_vector_type(8))) short s8v;     // 8 bf16 (4 VGPR) MFMA A/B frag
typedef __attribute__((ext_vector_type(4))) float f4v;     // MFMA C/D frag

static inline int cdiv(int a, int b) { return (a + b - 1) / b; }

__device__ inline u16 f2b(float f) {
    __hip_bfloat16 h = __float2bfloat16(f);
    union { __hip_bfloat16 b; u16 u; } c; c.b = h; return c.u;
}
__device__ inline float b2f(u16 u) {
    union { __hip_bfloat16 b; u16 u; } c; c.u = u; return __bfloat162float(c.b);
}

// transpose + split: W[b][K][N] -> T[b][N][K] hi(/lo)
template<bool WLO>
__global__ void tsplit_k(const float* __restrict__ W, u16* __restrict__ hi,
                         u16* __restrict__ lo, int K, int N, int total)
{
    int idx = blockIdx.x * 256 + threadIdx.x;
    if (idx >= total) return;
    int kn = K * N;
    int b = idx / kn, rem = idx - b * kn;
    int k = rem / N, n = rem - k * N;
    float v = W[idx];
    u16 h = f2b(v);
    int o = b * kn + n * K + k;
    hi[o] = h;
    if (WLO) lo[o] = f2b(v - b2f(h));
}

// W2T[L][r*16+c][kin] = sum_d W[L][r][kin][d] * (c<8 ? q[d][c] : k[d][c-8])
__global__ __launch_bounds__(256) void w2_k(const float* __restrict__ W0,
    const float* __restrict__ q0, const float* __restrict__ k0,
    const float* __restrict__ W1, const float* __restrict__ q1, const float* __restrict__ k1,
    u16* __restrict__ hi, u16* __restrict__ lo)
{
    int row = blockIdx.x * 4 + (threadIdx.x >> 6);   // 2304 rows
    int lane = threadIdx.x & 63;
    if (row >= 2304) return;
    int kin = row % 384;
    int lr3 = row / 384;
    int L = lr3 / 3, r = lr3 - L * 3;
    const float* W = (L ? W1 : W0) + ((size_t)r * 384 + kin) * 384;
    const float* qm = L ? q1 : q0;
    const float* km = L ? k1 : k0;
    float pq[16] = {};
    #pragma unroll
    for (int j = 0; j < 6; j++) {
        int d = lane + 64 * j;
        float x = W[d];
        #pragma unroll
        for (int h = 0; h < 8; h++) {
            pq[h]     = fmaf(x, qm[d * 8 + h], pq[h]);
            pq[8 + h] = fmaf(x, km[d * 8 + h], pq[8 + h]);
        }
    }
    #pragma unroll
    for (int o = 32; o; o >>= 1) {
        #pragma unroll
        for (int h = 0; h < 16; h++) pq[h] += __shfl_down(pq[h], o);
    }
    if (lane == 0) {
        #pragma unroll
        for (int c = 0; c < 16; c++) {
            u16 hh = f2b(pq[c]);
            size_t o = ((size_t)L * 48 + r * 16 + c) * 384 + kin;
            hi[o] = hh; lo[o] = f2b(pq[c] - b2f(hh));
        }
    }
}

// ---------------- small-K encoder GEMM ----------------
__global__ __launch_bounds__(256) void enc_gemm_k(const float* __restrict__ x, int K,
    const float* __restrict__ W, const float* __restrict__ bias,
    u16* __restrict__ out, float* __restrict__ stats)
{
    __shared__ float Wl[33 * 128];
    __shared__ float bl[128];
    __shared__ float red[8];
    int t = threadIdx.x;
    for (int i = t; i < K * 128; i += 256) Wl[i] = W[i];
    if (t < 128) bl[t] = bias[t];
    __syncthreads();
    int wid = t >> 6, lane = t & 63;
    float s1 = 0.f, s2 = 0.f;
    for (int rr = 0; rr < 8; rr++) {
        int n = blockIdx.x * 32 + wid * 8 + rr;
        if (n >= Nn) break;
        float xv = (lane < K) ? x[(size_t)n * K + lane] : 0.f;
        float a0 = 0.f, a1 = 0.f;
        for (int k = 0; k < K; k++) {
            float xk = __shfl(xv, k);
            a0 = fmaf(xk, Wl[k * 128 + 2 * lane], a0);
            a1 = fmaf(xk, Wl[k * 128 + 2 * lane + 1], a1);
        }
        a0 = fmaxf(a0 + bl[2 * lane], 0.f);
        a1 = fmaxf(a1 + bl[2 * lane + 1], 0.f);
        ((u32*)(out + (size_t)n * FD))[lane] = (u32)f2b(a0) | ((u32)f2b(a1) << 16);
        s1 += a0 + a1; s2 += a0 * a0 + a1 * a1;
    }
    #pragma unroll
    for (int o = 32; o; o >>= 1) { s1 += __shfl_down(s1, o); s2 += __shfl_down(s2, o); }
    if (lane == 0) { red[wid] = s1; red[4 + wid] = s2; }
    __syncthreads();
    if (t == 0) atomicAdd(&stats[0], red[0] + red[1] + red[2] + red[3]);
    if (t == 1) atomicAdd(&stats[1], red[4] + red[5] + red[6] + red[7]);
}

// ---------------- split-bf16 MFMA GEMM (LDS sized by TERMS) ----------------
#define USEI(i) ((i) < 2 || ((i) >= 4 && (i) < 6) || (TERMS >= 2 && ((i) == 2 || (i) == 3)) || (TERMS >= 3 && (i) >= 6))
template<bool BIAS, bool RELU, bool STATS, bool OB16, int TERMS, bool SWZ, bool AF32>
__global__ __launch_bounds__(256) void mgemm_k(
    const u16* __restrict__ Ahi, const u16* __restrict__ Alo, const float* __restrict__ Af,
    const u16* __restrict__ Bhi, const u16* __restrict__ Blo,
    const float* __restrict__ bias, void* __restrict__ Cv,
    int M, int K, int ldc, int bstride, float* __restrict__ stats)
{
    constexpr int NTILE = (TERMS >= 3) ? 4 : (TERMS + 1);   // 1->2, 2->3, 3->4
    // logical tile -> physical slot: 0=Ahi, 1=Alo, 2=Bhi, 3=Blo
    constexpr int tmap[4] = { 0, 1, (TERMS == 1 ? 1 : 2), 3 };
    __shared__ u16 lds[NTILE * 128 * 32];
    __shared__ float red[256];
    const int t = threadIdx.x;
    int brow, bcol, z;
    if (SWZ) {
        int d = blockIdx.x;
        int xcd = d & 7, s = d >> 3;
        int row = xcd + 8 * (s / 9);
        int c = s % 9;
        brow = row * 128;
        if (brow >= M) return;
        bcol = (c % 3) * 128;
        z = c / 3;
    } else {
        brow = blockIdx.x * 128; bcol = blockIdx.y * 128; z = blockIdx.z;
    }
    Bhi += (size_t)z * bstride;
    Blo += (size_t)z * bstride;
    float* Cf = OB16 ? nullptr : (float*)Cv + (size_t)z * M * ldc;
    u16*   Ch = OB16 ? (u16*)Cv + (size_t)z * M * ldc : nullptr;

    const int r0 = t >> 2, sl = t & 3;
    const int rA0 = min(brow + r0, M - 1);
    const int rA1 = min(brow + r0 + 64, M - 1);
    const u16* gsrc[8];
    gsrc[0] = Ahi + (size_t)rA0 * K + sl * 8;
    gsrc[1] = Ahi + (size_t)rA1 * K + sl * 8;
    gsrc[2] = Alo + (size_t)rA0 * K + sl * 8;
    gsrc[3] = Alo + (size_t)rA1 * K + sl * 8;
    gsrc[4] = Bhi + (size_t)(bcol + r0) * K + sl * 8;
    gsrc[5] = Bhi + (size_t)(bcol + r0 + 64) * K + sl * 8;
    gsrc[6] = Blo + (size_t)(bcol + r0) * K + sl * 8;
    gsrc[7] = Blo + (size_t)(bcol + r0 + 64) * K + sl * 8;
    const float* afsrc[2];
    if (AF32) {
        afsrc[0] = Af + (size_t)rA0 * K + sl * 8;
        afsrc[1] = Af + (size_t)rA1 * K + sl * 8;
    }
    const int swz = (sl ^ (r0 & 3)) << 3;
    int ldst[8];
    #pragma unroll
    for (int i = 0; i < 8; i++) {
        int tile = tmap[i >> 1], row = r0 + 64 * (i & 1);
        ldst[i] = tile * 4096 + row * 32 + swz;
    }

    const int l = t & 63, w = t >> 6;
    const int wr = (w >> 1) * 64, wc = (w & 1) * 64;
    const int lr = l & 15, kq = l >> 4;

    f4v acc[4][4] = {};
    const int NK = K >> 5;

    #define LDA32(i, ko) ({ \
        float4 f0_ = *(const float4*)(afsrc[i] + (ko)); \
        float4 f1_ = *(const float4*)(afsrc[i] + (ko) + 4); \
        s8v r_; \
        r_[0] = (short)f2b(f0_.x); r_[1] = (short)f2b(f0_.y); \
        r_[2] = (short)f2b(f0_.z); r_[3] = (short)f2b(f0_.w); \
        r_[4] = (short)f2b(f1_.x); r_[5] = (short)f2b(f1_.y); \
        r_[6] = (short)f2b(f1_.z); r_[7] = (short)f2b(f1_.w); \
        r_; })

    s8v stg[8];
    #pragma unroll
    for (int i = 0; i < 8; i++) {
        if (AF32 && i < 2) stg[i] = LDA32(i, 0);
        else if (!(AF32 && i < 2) && USEI(i)) stg[i] = *(const s8v*)gsrc[i];
    }

    for (int kc = 0; kc < NK; kc++) {
        if (kc) __syncthreads();
        #pragma unroll
        for (int i = 0; i < 8; i++) if (USEI(i)) *(s8v*)(lds + ldst[i]) = stg[i];
        __syncthreads();
        if (kc + 1 < NK) {
            const int ko = (kc + 1) * 32;
            #pragma unroll
            for (int i = 0; i < 8; i++) {
                if (AF32 && i < 2) stg[i] = LDA32(i, ko);
                else if (!(AF32 && i < 2) && USEI(i)) stg[i] = *(const s8v*)(gsrc[i] + ko);
            }
        }
        #define LDR(T, row) (*(const s8v*)(lds + tmap[T] * 4096 + (row) * 32 + ((kq ^ ((row) & 3)) << 3)))
        s8v bh[4], bl[4];
        #pragma unroll
        for (int tn = 0; tn < 4; tn++) {
            int rb = wc + tn * 16 + lr;
            bh[tn] = LDR(2, rb);
            if (TERMS >= 3) bl[tn] = LDR(3, rb);
        }
        #pragma unroll
        for (int tm = 0; tm < 4; tm++) {
            int ra = wr + tm * 16 + lr;
            s8v ah = LDR(0, ra);
            s8v al;
            if (TERMS >= 2) al = LDR(1, ra);
            #pragma unroll
            for (int tn = 0; tn < 4; tn++) {
                acc[tm][tn] = __builtin_amdgcn_mfma_f32_16x16x32_bf16(ah, bh[tn], acc[tm][tn], 0, 0, 0);
                if (TERMS >= 2)
                    acc[tm][tn] = __builtin_amdgcn_mfma_f32_16x16x32_bf16(al, bh[tn], acc[tm][tn], 0, 0, 0);
                if (TERMS >= 3)
                    acc[tm][tn] = __builtin_amdgcn_mfma_f32_16x16x32_bf16(ah, bl[tn], acc[tm][tn], 0, 0, 0);
            }
        }
        #undef LDR
    }
    #undef LDA32

    float s1 = 0.f, s2 = 0.f;
    #pragma unroll
    for (int tm = 0; tm < 4; tm++) {
        #pragma unroll
        for (int rg = 0; rg < 4; rg++) {
            int row = brow + wr + tm * 16 + kq * 4 + rg;
            if (row < M) {
                #pragma unroll
                for (int tn = 0; tn < 4; tn++) {
                    int col = bcol + wc + tn * 16 + lr;
                    float v = acc[tm][tn][rg];
                    if (BIAS) v += bias[col];
                    if (RELU) v = fmaxf(v, 0.f);
                    if (OB16) Ch[(size_t)row * ldc + col] = f2b(v);
                    else      Cf[(size_t)row * ldc + col] = v;
                    if (STATS) { s1 += v; s2 += v * v; }
                }
            }
        }
    }
    if (STATS) {
        __syncthreads();
        red[t] = s1; __syncthreads();
        for (int o = 128; o; o >>= 1) { if (t < o) red[t] += red[t + o]; __syncthreads(); }
        if (t == 0) atomicAdd(&stats[0], red[0]);
        __syncthreads();
        red[t] = s2; __syncthreads();
        for (int o = 128; o; o >>= 1) { if (t < o) red[t] += red[t + o]; __syncthreads(); }
        if (t == 0) atomicAdd(&stats[1], red[0]);
    }
}
#undef USEI

// ---------------- fused classifier ----------------
template<bool DOSM>
__global__ __launch_bounds__(256) void mcls_k(
    const u16* __restrict__ A, const u16* __restrict__ Bh, const float* __restrict__ b1,
    const u16* __restrict__ w2hi, const u16* __restrict__ w2lo, const float* __restrict__ b2,
    float* __restrict__ outp, float* __restrict__ prior)
{
    __shared__ u16 lds[128 * 132];
    __shared__ u16 w2lds[2][32 * 132];
    const int t = threadIdx.x;
    const int brow = blockIdx.x * 128;

    for (int i = t; i < 512; i += 256) {
        int row = i >> 4, c8 = (i & 15) * 8;
        *(s8v*)&w2lds[0][row * 132 + c8] = *(const s8v*)(w2hi + row * 128 + c8);
        *(s8v*)&w2lds[1][row * 132 + c8] = *(const s8v*)(w2lo + row * 128 + c8);
    }

    const int r0 = t >> 2, sl = t & 3;
    const int rA0 = min(brow + r0, Nn - 1);
    const int rA1 = min(brow + r0 + 64, Nn - 1);
    const u16* gA0 = A + (size_t)rA0 * FD + sl * 8;
    const u16* gA1 = A + (size_t)rA1 * FD + sl * 8;
    const u16* gB0 = Bh + (size_t)r0 * FD + sl * 8;
    const u16* gB1 = Bh + (size_t)(r0 + 64) * FD + sl * 8;
    const int swz = (sl ^ (r0 & 3)) << 3;
    const int la0 = r0 * 32 + swz, la1 = (r0 + 64) * 32 + swz;
    const int lb0 = 2 * 4096 + r0 * 32 + swz, lb1 = 2 * 4096 + (r0 + 64) * 32 + swz;

    const int l = t & 63, w = t >> 6;
    const int wr = (w >> 1) * 64, wc = (w & 1) * 64;
    const int lr = l & 15, kq = l >> 4;

    f4v acc[4][4] = {};
    s8v sA0 = *(const s8v*)gA0, sA1 = *(const s8v*)gA1;
    s8v sB0 = *(const s8v*)gB0, sB1 = *(const s8v*)gB1;
    for (int kc = 0; kc < 12; kc++) {
        if (kc) __syncthreads();
        *(s8v*)(lds + la0) = sA0; *(s8v*)(lds + la1) = sA1;
        *(s8v*)(lds + lb0) = sB0; *(s8v*)(lds + lb1) = sB1;
        __syncthreads();
        if (kc + 1 < 12) {
            int ko = (kc + 1) * 32;
            sA0 = *(const s8v*)(gA0 + ko); sA1 = *(const s8v*)(gA1 + ko);
            sB0 = *(const s8v*)(gB0 + ko); sB1 = *(const s8v*)(gB1 + ko);
        }
        #define LDR(T, row) (*(const s8v*)(lds + (T) * 4096 + (row) * 32 + ((kq ^ ((row) & 3)) << 3)))
        s8v bh[4];
        #pragma unroll
        for (int tn = 0; tn < 4; tn++) bh[tn] = LDR(2, wc + tn * 16 + lr);
        #pragma unroll
        for (int tm = 0; tm < 4; tm++) {
            s8v ah = LDR(0, wr + tm * 16 + lr);
            #pragma unroll
            for (int tn = 0; tn < 4; tn++)
                acc[tm][tn] = __builtin_amdgcn_mfma_f32_16x16x32_bf16(ah, bh[tn], acc[tm][tn], 0, 0, 0);
        }
        #undef LDR
    }
    __syncthreads();

    #pragma unroll
    for (int tm = 0; tm < 4; tm++)
        #pragma unroll
        for (int rg = 0; rg < 4; rg++) {
            int row = wr + tm * 16 + kq * 4 + rg;
            #pragma unroll
            for (int tn = 0; tn < 4; tn++) {
                int col = wc + tn * 16 + lr;
                lds[row * 132 + col] = f2b(fmaxf(acc[tm][tn][rg] + b1[col], 0.f));
            }
        }
    __syncthreads();

    f4v a2[2][2] = {};
    #pragma unroll
    for (int ks = 0; ks < 4; ks++) {
        #pragma unroll
        for (int rf = 0; rf < 2; rf++) {
            int ar = w * 32 + rf * 16 + lr;
            s8v av = *(const s8v*)&lds[ar * 132 + ks * 32 + kq * 8];
            #pragma unroll
            for (int cf = 0; cf < 2; cf++) {
                s8v bhv = *(const s8v*)&w2lds[0][(cf * 16 + lr) * 132 + ks * 32 + kq * 8];
                s8v blv = *(const s8v*)&w2lds[1][(cf * 16 + lr) * 132 + ks * 32 + kq * 8];
                a2[rf][cf] = __builtin_amdgcn_mfma_f32_16x16x32_bf16(av, bhv, a2[rf][cf], 0, 0, 0);
                a2[rf][cf] = __builtin_amdgcn_mfma_f32_16x16x32_bf16(av, blv, a2[rf][cf], 0, 0, 0);
            }
        }
    }
    #pragma unroll
    for (int rf = 0; rf < 2; rf++) {
        #pragma unroll
        for (int rg = 0; rg < 4; rg++) {
            int grow = brow + w * 32 + rf * 16 + kq * 4 + rg;
            float v0 = a2[rf][0][rg] + b2[lr];
            float v1 = a2[rf][1][rg] + b2[16 + lr];
            if (grow < Nn) {
                outp[(size_t)grow * 32 + lr] = v0;
                outp[(size_t)grow * 32 + 16 + lr] = v1;
            }
            if (DOSM) {
                float m = fmaxf(v0, v1);
                m = fmaxf(m, __shfl_xor(m, 1));
                m = fmaxf(m, __shfl_xor(m, 2));
                m = fmaxf(m, __shfl_xor(m, 4));
                m = fmaxf(m, __shfl_xor(m, 8));
                float e0 = __expf(v0 - m), e1 = __expf(v1 - m);
                float s = e0 + e1;
                s += __shfl_xor(s, 1); s += __shfl_xor(s, 2);
                s += __shfl_xor(s, 4); s += __shfl_xor(s, 8);
                if (grow < Nn) {
                    float rs = 1.f / s;
                    prior[(size_t)grow * 33 + lr] = e0 * rs;
                    prior[(size_t)grow * 33 + 16 + lr] = e1 * rs;
                    if (lr == 0) prior[(size_t)grow * 33 + 32] = rs;
                }
            }
        }
    }
}

// ---------------- projh GEMM: QIK[Nn,48] = HS(bf16) @ W2T[48,384]^T ----------------
__global__ __launch_bounds__(256) void projh_k(const u16* __restrict__ hs,
    const u16* __restrict__ w2hi, const u16* __restrict__ w2lo, float* __restrict__ qik)
{
    __shared__ u16 a_lds[128 * 32];
    __shared__ u16 b_lds[2][48 * 392];
    int t = threadIdx.x;
    int brow = blockIdx.x * 128;

    for (int i = t; i < 2304; i += 256) {
        int col = i / 48, c8 = (i - col * 48) * 8;
        *(s8v*)&b_lds[0][col * 392 + c8] = *(const s8v*)(w2hi + col * 384 + c8);
        *(s8v*)&b_lds[1][col * 392 + c8] = *(const s8v*)(w2lo + col * 384 + c8);
    }

    int ar = t >> 1, sl0 = (t & 1) * 2;
    int grow = min(brow + ar, Nn - 1);
    const u16* asrc = hs + (size_t)grow * FD;
    int adst0 = ar * 32 + ((sl0 ^ (ar & 3)) << 3);
    int adst1 = ar * 32 + (((sl0 + 1) ^ (ar & 3)) << 3);

    int l = t & 63, w = t >> 6;
    int lr = l & 15, kq = l >> 4;
    f4v acc[2][3] = {};

    s8v stg0 = *(const s8v*)(asrc + sl0 * 8);
    s8v stg1 = *(const s8v*)(asrc + sl0 * 8 + 8);
    for (int kc = 0; kc < 12; kc++) {
        if (kc) __syncthreads();
        *(s8v*)&a_lds[adst0] = stg0;
        *(s8v*)&a_lds[adst1] = stg1;
        __syncthreads();
        if (kc + 1 < 12) {
            int ko = (kc + 1) * 32 + sl0 * 8;
            stg0 = *(const s8v*)(asrc + ko);
            stg1 = *(const s8v*)(asrc + ko + 8);
        }
        s8v bh[3], bl[3];
        #pragma unroll
        for (int cf = 0; cf < 3; cf++) {
            bh[cf] = *(const s8v*)&b_lds[0][(cf * 16 + lr) * 392 + kc * 32 + kq * 8];
            bl[cf] = *(const s8v*)&b_lds[1][(cf * 16 + lr) * 392 + kc * 32 + kq * 8];
        }
        #pragma unroll
        for (int rf = 0; rf < 2; rf++) {
            int rr = w * 32 + rf * 16 + lr;
            s8v a = *(const s8v*)&a_lds[rr * 32 + ((kq ^ (rr & 3)) << 3)];
            #pragma unroll
            for (int cf = 0; cf < 3; cf++) {
                acc[rf][cf] = __builtin_amdgcn_mfma_f32_16x16x32_bf16(a, bh[cf], acc[rf][cf], 0, 0, 0);
                acc[rf][cf] = __builtin_amdgcn_mfma_f32_16x16x32_bf16(a, bl[cf], acc[rf][cf], 0, 0, 0);
            }
        }
    }
    #pragma unroll
    for (int rf = 0; rf < 2; rf++)
        #pragma unroll
        for (int cf = 0; cf < 3; cf++)
            #pragma unroll
            for (int rg = 0; rg < 4; rg++) {
                int row = brow + w * 32 + rf * 16 + kq * 4 + rg;
                if (row < Nn) qik[(size_t)row * 48 + cf * 16 + lr] = acc[rf][cf][rg];
            }
}

// scalar-LN of a 128-col block (bf16 pre-norm, pre-offset) from RAW sums -> bf16 hi
__global__ __launch_bounds__(256) void enc_norm_k(const u16* __restrict__ H,
                           const float* __restrict__ w, const float* __restrict__ b,
                           const float* __restrict__ stats, float cntinv, u16* __restrict__ hi)
{
    int i = blockIdx.x * 256 + threadIdx.x;
    if (i >= Nn * 32) return;
    int n = i >> 5, c4 = i & 31;
    float m = stats[0] * cntinv;
    float var = stats[1] * cntinv - m * m;
    float s = 1.f / (sqrtf(fmaxf(var, 0.f)) + EPS);
    float4 wv = ((const float4*)w)[c4];
    float4 bv = ((const float4*)b)[c4];
    uint2 yv = ((const uint2*)(H + (size_t)n * FD))[c4];
    ushort4 hh;
    hh.x = f2b((b2f((u16)(yv.x & 0xffffu)) - m) * s * wv.x + bv.x);
    hh.y = f2b((b2f((u16)(yv.x >> 16))     - m) * s * wv.y + bv.y);
    hh.z = f2b((b2f((u16)(yv.y & 0xffffu)) - m) * s * wv.z + bv.z);
    hh.w = f2b((b2f((u16)(yv.y >> 16))     - m) * s * wv.w + bv.w);
    ((ushort4*)(hi + (size_t)n * FD))[c4] = hh;
}

__global__ void edge_count_k(const int* __restrict__ e0, const int* __restrict__ e1,
                             const int* __restrict__ e2, int* __restrict__ cnt)
{
    int e = blockIdx.x * 256 + threadIdx.x;
    if (e >= ETOT) return;
    int r = e / EREL, i = e - r * EREL;
    const int* ei = (r == 0) ? e0 : (r == 1) ? e1 : e2;
    atomicAdd(&cnt[ei[EREL + i]], 1);
}

__global__ void edge_fill_k(const int* __restrict__ e0, const int* __restrict__ e1,
                            const int* __restrict__ e2, int* __restrict__ cursor,
                            int* __restrict__ eidx)
{
    int e = blockIdx.x * 256 + threadIdx.x;
    if (e >= ETOT) return;
    int r = e / EREL, i = e - r * EREL;
    const int* ei = (r == 0) ? e0 : (r == 1) ? e1 : e2;
    int src = ei[i], dst = ei[EREL + i];
    int pos = atomicAdd(&cursor[dst], 1);
    eidx[pos] = src | (r << 24);
}

// exclusive scan via per-wave shuffle scan + 16-wave LDS combine
__global__ __launch_bounds__(1024) void scan_k(const int* __restrict__ cnt,
                                               int* __restrict__ rowptr, int* __restrict__ cursor)
{
    __shared__ int wsum[16], wpre[16];
    __shared__ int carry, tot;
    int t = threadIdx.x, lane = t & 63, wid = t >> 6;
    if (t == 0) carry = 0;
    __syncthreads();
    for (int base = 0; base < Nn; base += 1024) {
        int i = base + t;
        int v = (i < Nn) ? cnt[i] : 0;
        int s = v;
        #pragma unroll
        for (int o = 1; o < 64; o <<= 1) {
            int x = __shfl_up(s, o);
            if (lane >= o) s += x;
        }
        if (lane == 63) wsum[wid] = s;
        __syncthreads();
        if (t < 16) {
            int wv = wsum[t];
            int ws = wv;
            #pragma unroll
            for (int o = 1; o < 16; o <<= 1) {
                int x = __shfl_up(ws, o);
                if (t >= o) ws += x;
            }
            wpre[t] = ws - wv;
            if (t == 15) tot = ws;
        }
        __syncthreads();
        if (i < Nn) {
            int ex = carry + wpre[wid] + s - v;
            rowptr[i] = ex; cursor[i] = ex;
        }
        __syncthreads();
        if (t == 0) carry += tot;
    }
    __syncthreads();
    if (t == 0) rowptr[Nn] = carry;
}

// per-graph node counts via LDS histogram
__global__ __launch_bounds__(256) void gcount_k(const int* __restrict__ batch, int* __restrict__ gcnt)
{
    __shared__ int bins[NG];
    int t = threadIdx.x;
    if (t < NG) bins[t] = 0;
    __syncthreads();
    int n = blockIdx.x * 256 + t;
    if (n < Nn) atomicAdd(&bins[batch[n]], 1);
    __syncthreads();
    if (t < NG && bins[t]) atomicAdd(&gcnt[t], bins[t]);
}

// RGAT aggregation, softmax fused. One wave per node, 4x edge unroll, dwordx3 gather.
// Non-temporal hints on streamed residual read + output write (preserve L2 for XR gather).
__global__ __launch_bounds__(256) void aggr_k(const u16* __restrict__ xr,
    const float* __restrict__ qik, const int* __restrict__ rowptr, const int* __restrict__ eidx,
    const float* __restrict__ bias, const u16* __restrict__ hinb,
    const int* __restrict__ batch, u16* __restrict__ outb,
    float* __restrict__ gsum, float* __restrict__ gsq)
{
    __shared__ float ls[NG], lq[NG];
    int t = threadIdx.x;
    if (t < NG) { ls[t] = 0.f; lq[t] = 0.f; }
    __syncthreads();
    int node = blockIdx.x * 4 + (t >> 6);
    int lane = t & 63;
    int e0 = rowptr[node], e1 = rowptr[node + 1];
    int hd = lane >> 3;
    float qv = (lane < 48) ? qik[(size_t)node * 48 + lane] : 0.f;
    float den = 0.f;
    float acc[6] = {};

    int e = e0;
    while (e + 4 <= e1) {
        int p0 = eidx[e], p1 = eidx[e + 1], p2 = eidx[e + 2], p3 = eidx[e + 3];
        int n0 = p0 & 0xFFFFFF, et0 = p0 >> 24;
        int n1 = p1 & 0xFFFFFF, et1 = p1 >> 24;
        int n2 = p2 & 0xFFFFFF, et2 = p2 >> 24;
        int n3 = p3 & 0xFFFFFF, et3 = p3 >> 24;
        float kv0 = (lane < 8) ? qik[(size_t)n0 * 48 + et0 * 16 + 8 + lane] : 0.f;
        float kv1 = (lane < 8) ? qik[(size_t)n1 * 48 + et1 * 16 + 8 + lane] : 0.f;
        float kv2 = (lane < 8) ? qik[(size_t)n2 * 48 + et2 * 16 + 8 + lane] : 0.f;
        float kv3 = (lane < 8) ? qik[(size_t)n3 * 48 + et3 * 16 + 8 + lane] : 0.f;
        const u32* r0 = (const u32*)(xr + ((size_t)et0 * Nn + n0) * FD);
        const u32* r1 = (const u32*)(xr + ((size_t)et1 * Nn + n1) * FD);
        const u32* r2 = (const u32*)(xr + ((size_t)et2 * Nn + n2) * FD);
        const u32* r3 = (const u32*)(xr + ((size_t)et3 * Nn + n3) * FD);
        u32 u0[3], u1[3], u2[3], u3[3];
        #pragma unroll
        for (int j = 0; j < 3; j++) u0[j] = r0[lane * 3 + j];
        #pragma unroll
        for (int j = 0; j < 3; j++) u1[j] = r1[lane * 3 + j];
        #pragma unroll
        for (int j = 0; j < 3; j++) u2[j] = r2[lane * 3 + j];
        #pragma unroll
        for (int j = 0; j < 3; j++) u3[j] = r3[lane * 3 + j];
        float qq0 = __shfl(qv, et0 * 16 + (lane & 7));
        float qq1 = __shfl(qv, et1 * 16 + (lane & 7));
        float qq2 = __shfl(qv, et2 * 16 + (lane & 7));
        float qq3 = __shfl(qv, et3 * 16 + (lane & 7));
        float ex0 = 0.f, ex1 = 0.f, ex2 = 0.f, ex3 = 0.f;
        if (lane < 8) {
            float a0 = qq0 + kv0; a0 = (a0 > 0.f) ? a0 : 0.2f * a0; ex0 = __expf(a0);
            float a1 = qq1 + kv1; a1 = (a1 > 0.f) ? a1 : 0.2f * a1; ex1 = __expf(a1);
            float a2 = qq2 + kv2; a2 = (a2 > 0.f) ? a2 : 0.2f * a2; ex2 = __expf(a2);
            float a3 = qq3 + kv3; a3 = (a3 > 0.f) ? a3 : 0.2f * a3; ex3 = __expf(a3);
        }
        den += ex0 + ex1 + ex2 + ex3;
        float w0 = __shfl(ex0, hd), w1 = __shfl(ex1, hd);
        float w2 = __shfl(ex2, hd), w3 = __shfl(ex3, hd);
        #pragma unroll
        for (int j = 0; j < 3; j++) {
            acc[2*j]   = fmaf(w0, __uint_as_float(u0[j] << 16), acc[2*j]);
            acc[2*j+1] = fmaf(w0, __uint_as_float(u0[j] & 0xffff0000u), acc[2*j+1]);
            acc[2*j]   = fmaf(w1, __uint_as_float(u1[j] << 16), acc[2*j]);
            acc[2*j+1] = fmaf(w1, __uint_as_float(u1[j] & 0xffff0000u), acc[2*j+1]);
            acc[2*j]   = fmaf(w2, __uint_as_float(u2[j] << 16), acc[2*j]);
            acc[2*j+1] = fmaf(w2, __uint_as_float(u2[j] & 0xffff0000u), acc[2*j+1]);
            acc[2*j]   = fmaf(w3, __uint_as_float(u3[j] << 16), acc[2*j]);
            acc[2*j+1] = fmaf(w3, __uint_as_float(u3[j] & 0xffff0000u), acc[2*j+1]);
        }
        e += 4;
    }
    for (; e < e1; e++) {
        int p = eidx[e];
        int sn = p & 0xFFFFFF, et = p >> 24;
        float kv = (lane < 8) ? qik[(size_t)sn * 48 + et * 16 + 8 + lane] : 0.f;
        const u32* rr = (const u32*)(xr + ((size_t)et * Nn + sn) * FD);
        u32 u[3];
        #pragma unroll
        for (int j = 0; j < 3; j++) u[j] = rr[lane * 3 + j];
        float qq = __shfl(qv, et * 16 + (lane & 7));
        float ex = 0.f;
        if (lane < 8) { float a = qq + kv; a = (a > 0.f) ? a : 0.2f * a; ex = __expf(a); }
        den += ex;
        float wv_ = __shfl(ex, hd);
        #pragma unroll
        for (int j = 0; j < 3; j++) {
            acc[2*j]   = fmaf(wv_, __uint_as_float(u[j] << 16), acc[2*j]);
            acc[2*j+1] = fmaf(wv_, __uint_as_float(u[j] & 0xffff0000u), acc[2*j+1]);
        }
    }

    float dh = __shfl(den, hd);
    float rcp = 1.f / (dh + 1e-16f);
    const u32* hp = (const u32*)(hinb + (size_t)node * FD);
    u32* op = (u32*)(outb + (size_t)node * FD);
    float s1 = 0.f, s2 = 0.f;
    #pragma unroll
    for (int j = 0; j < 3; j++) {
        int c = lane * 6 + 2 * j;
        float2 bv = *(const float2*)(bias + c);
        u32 hb = __builtin_nontemporal_load(hp + lane * 3 + j);
        float vx = acc[2*j] * rcp + bv.x;
        float vy = acc[2*j+1] * rcp + bv.y;
        vx = (vx > 0.f) ? vx : expm1f(vx);
        vy = (vy > 0.f) ? vy : expm1f(vy);
        vx += b2f((u16)(hb & 0xffffu));
        vy += b2f((u16)(hb >> 16));
        __builtin_nontemporal_store((u32)f2b(vx) | ((u32)f2b(vy) << 16), op + lane * 3 + j);
        s1 += vx + vy; s2 += vx * vx + vy * vy;
    }
    #pragma unroll
    for (int o = 32; o; o >>= 1) { s1 += __shfl_down(s1, o); s2 += __shfl_down(s2, o); }
    int g = batch[node];
    if (lane == 0) { atomicAdd(&ls[g], s1); atomicAdd(&lq[g], s2); }
    __syncthreads();
    if (t < NG && (ls[t] != 0.f || lq[t] != 0.f)) {
        atomicAdd(&gsum[t], ls[t]);
        atomicAdd(&gsq[t], lq[t]);
    }
}

// graph-LN from raw sums, bf16 input -> bf16 hi
__global__ __launch_bounds__(256) void gnorm_split_k(const u16* __restrict__ yb,
    const int* __restrict__ batch, const float* __restrict__ gsum, const float* __restrict__ gsq,
    const int* __restrict__ gcnt, const float* __restrict__ w, const float* __restrict__ b,
    u16* __restrict__ hi)
{
    int i = blockIdx.x * 256 + threadIdx.x;
    if (i >= Nn * (FD / 4)) return;
    int n = i / 96;
    int c4 = i - n * 96;
    int g = batch[n];
    float norm = fmaxf((float)gcnt[g], 1.f) * (float)FD;
    float m = gsum[g] / norm;
    float var = gsq[g] / norm - m * m;
    float rstd = rsqrtf(var + EPS);
    float4 wv = ((const float4*)w)[c4];
    float4 bv = ((const float4*)b)[c4];
    uint2 yv = ((const uint2*)yb)[i];
    ushort4 hh;
    hh.x = f2b((b2f((u16)(yv.x & 0xffffu)) - m) * rstd * wv.x + bv.x);
    hh.y = f2b((b2f((u16)(yv.x >> 16))     - m) * rstd * wv.y + bv.y);
    hh.z = f2b((b2f((u16)(yv.y & 0xffffu)) - m) * rstd * wv.z + bv.z);
    hh.w = f2b((b2f((u16)(yv.y >> 16))     - m) * rstd * wv.w + bv.w);
    ((ushort4*)hi)[i] = hh;
}

extern "C" void kernel_launch(void* const* d_in, const int* in_sizes, int n_in,
                              void* d_out, int out_size, void* d_ws, size_t ws_size,
                              hipStream_t stream)
{
    const float* x_visual = (const float*)d_in[0];
    const float* x_geom   = (const float*)d_in[1];
    const float* x_prior  = (const float*)d_in[2];
    const int* ei0   = (const int*)d_in[3];
    const int* ei1   = (const int*)d_in[4];
    const int* ei2   = (const int*)d_in[5];
    const int* batch = (const int*)d_in[6];
    const float* vis_W = (const float*)d_in[7];  const float* vis_b = (const float*)d_in[8];
    const float* vis_lnw = (const float*)d_in[9]; const float* vis_lnb = (const float*)d_in[10];
    const float* geo_W = (const float*)d_in[11]; const float* geo_b = (const float*)d_in[12];
    const float* geo_lnw = (const float*)d_in[13]; const float* geo_lnb = (const float*)d_in[14];
    const float* pri_W = (const float*)d_in[15]; const float* pri_b = (const float*)d_in[16];
    const float* pri_lnw = (const float*)d_in[17]; const float* pri_lnb = (const float*)d_in[18];
    const float* rgat_W[2]    = { (const float*)d_in[19], (const float*)d_in[25] };
    const float* rgat_q[2]    = { (const float*)d_in[20], (const float*)d_in[26] };
    const float* rgat_kk[2]   = { (const float*)d_in[21], (const float*)d_in[27] };
    const float* rgat_bias[2] = { (const float*)d_in[22], (const float*)d_in[28] };
    const float* ln_w[2]      = { (const float*)d_in[23], (const float*)d_in[29] };
    const float* ln_b[2]      = { (const float*)d_in[24], (const float*)d_in[30] };
    const float* cls_W1 = (const float*)d_in[31]; const float* cls_b1 = (const float*)d_in[32];
    const float* cls_W2 = (const float*)d_in[33]; const float* cls_b2 = (const float*)d_in[34];
    float* OUT = (float*)d_out;

    // ---------------- workspace layout ----------------
    float* ws = (float*)d_ws;
    float* XRreg = ws;
    u16*   XR16  = (u16*)XRreg;
    float* HCAT  = XRreg + (size_t)3 * Nn * FD;
    u16*   HENC  = (u16*)HCAT;
    float* HA    = HCAT + (size_t)Nn * FD;
    float* HB    = HA + (size_t)Nn * FD;
    float* PRIOR = HB + (size_t)Nn * FD;
    float* QIK   = PRIOR + (size_t)Nn * 33;
    u16* HS0_HI  = (u16*)(QIK + (size_t)Nn * 48);
    u16* HS0_LO  = HS0_HI + (size_t)Nn * FD;
    u16* HS1_HI  = HS0_LO + (size_t)Nn * FD;
    u16* HS1_LO  = HS1_HI + (size_t)Nn * FD;
    u16* RW_HI   = HS1_LO + (size_t)Nn * FD;
    u16* RW_LO   = RW_HI + (size_t)2 * 3 * 384 * 384;
    u16* VW_HI   = RW_LO + (size_t)2 * 3 * 384 * 384;
    u16* VW_LO   = VW_HI + (size_t)128 * 1024;
    u16* CW_HI   = VW_LO + (size_t)128 * 1024;
    u16* W2T_HI  = CW_HI + (size_t)128 * 384;
    u16* W2T_LO  = W2T_HI + (size_t)32 * 128;
    u16* W2_HI   = W2T_LO + (size_t)32 * 128;
    u16* W2_LO   = W2_HI + (size_t)2 * 48 * 384;
    float* GS    = (float*)(W2_LO + (size_t)2 * 48 * 384);
    float* STATS = GS + 512;
    int* CNT    = (int*)(STATS + 8);
    int* ROWPTR = CNT + Nn;
    int* CURSOR = ROWPTR + Nn + 1;
    int* EIDX   = CURSOR + Nn;
    int* GCNT   = EIDX + ETOT;
    u16* HS2_HI = (u16*)(XRreg + (size_t)12 * 1000 * 1000);
    u16* YB0 = (u16*)HA;
    u16* YB1 = (u16*)HB;

    // ---------------- CSR build ----------------
    hipMemsetAsync(CNT, 0, Nn * sizeof(int), stream);
    edge_count_k<<<cdiv(ETOT, 256), 256, 0, stream>>>(ei0, ei1, ei2, CNT);
    scan_k<<<1, 1024, 0, stream>>>(CNT, ROWPTR, CURSOR);
    edge_fill_k<<<cdiv(ETOT, 256), 256, 0, stream>>>(ei0, ei1, ei2, CURSOR, EIDX);
    hipMemsetAsync(GCNT, 0, 64 * sizeof(int), stream);
    gcount_k<<<cdiv(Nn, 256), 256, 0, stream>>>(batch, GCNT);
    hipMemsetAsync(GS, 0, 520 * sizeof(float), stream);

    // ---------------- weight conversions ----------------
    tsplit_k<false><<<cdiv(3 * 384 * 384, 256), 256, 0, stream>>>(rgat_W[0], RW_HI, RW_LO, 384, 384, 3 * 384 * 384);
    tsplit_k<false><<<cdiv(3 * 384 * 384, 256), 256, 0, stream>>>(rgat_W[1], RW_HI + 3 * 384 * 384, RW_LO, 384, 384, 3 * 384 * 384);
    tsplit_k<false><<<cdiv(1024 * 128, 256), 256, 0, stream>>>(vis_W, VW_HI, VW_LO, 1024, 128, 1024 * 128);
    tsplit_k<false><<<cdiv(384 * 128, 256), 256, 0, stream>>>(cls_W1, CW_HI, nullptr, 384, 128, 384 * 128);
    tsplit_k<true><<<cdiv(128 * 32, 256), 256, 0, stream>>>(cls_W2, W2T_HI, W2T_LO, 128, 32, 128 * 32);
    w2_k<<<576, 256, 0, stream>>>(rgat_W[0], rgat_q[0], rgat_kk[0],
                                  rgat_W[1], rgat_q[1], rgat_kk[1], W2_HI, W2_LO);

    const int MB = cdiv(Nn, 128);   // 157
    const int XRBLK = 160 * 9;      // XCD-swizzled
    const float cinv = 1.f / ((float)Nn * 128.f);

    // ---------------- vis encoder ----------------
    mgemm_k<true, true, true, true, 1, false, true><<<dim3(MB, 1, 1), 256, 0, stream>>>(
        nullptr, nullptr, x_visual, VW_HI, VW_LO, vis_b, HENC, Nn, 1024, FD, 0, STATS + 0);
    enc_norm_k<<<cdiv(Nn * 32, 256), 256, 0, stream>>>(HENC, vis_lnw, vis_lnb, STATS + 0, cinv, HS0_HI);

    // ---------------- geo encoder ----------------
    enc_gemm_k<<<cdiv(Nn, 32), 256, 0, stream>>>(x_geom, 6, geo_W, geo_b, HENC + 128, STATS + 2);
    enc_norm_k<<<cdiv(Nn * 32, 256), 256, 0, stream>>>(HENC + 128, geo_lnw, geo_lnb, STATS + 2, cinv, HS0_HI + 128);

    for (int t = 0; t < 2; t++) {
        const float* pin = t ? PRIOR : x_prior;
        enc_gemm_k<<<cdiv(Nn, 32), 256, 0, stream>>>(pin, 33, pri_W, pri_b, HENC + 256, STATS + 4 + 2 * t);
        enc_norm_k<<<cdiv(Nn * 32, 256), 256, 0, stream>>>(HENC + 256, pri_lnw, pri_lnb, STATS + 4 + 2 * t, cinv, HS0_HI + 256);

        for (int L = 0; L < 2; L++) {
            const u16* ahi = L ? HS1_HI : HS0_HI;
            u16* yout = L ? YB1 : YB0;
            u16* snorm = L ? HS2_HI : HS1_HI;
            float* gsum = GS + (t * 2 + L) * 128;
            mgemm_k<false, false, false, true, 1, true, false><<<dim3(XRBLK, 1, 1), 256, 0, stream>>>(
                ahi, ahi, nullptr, RW_HI + (size_t)L * 3 * 384 * 384, RW_LO,
                nullptr, XR16, Nn, 384, FD, 384 * 384, nullptr);
            projh_k<<<MB, 256, 0, stream>>>(ahi,
                W2_HI + (size_t)L * 48 * 384, W2_LO + (size_t)L * 48 * 384, QIK);
            aggr_k<<<cdiv(Nn, 4), 256, 0, stream>>>(XR16, QIK, ROWPTR, EIDX, rgat_bias[L],
                                                    ahi, batch, yout, gsum, gsum + 64);
            gnorm_split_k<<<cdiv(Nn * 96, 256), 256, 0, stream>>>(
                yout, batch, gsum, gsum + 64, GCNT, ln_w[L], ln_b[L], snorm);
        }

        if (t == 0)
            mcls_k<true><<<dim3(MB, 1, 1), 256, 0, stream>>>(
                HS2_HI, CW_HI, cls_b1, W2T_HI, W2T_LO, cls_b2, OUT, PRIOR);
        else
            mcls_k<false><<<dim3(MB, 1, 1), 256, 0, stream>>>(
                HS2_HI, CW_HI, cls_b1, W2T_HI, W2T_LO, cls_b2, OUT, nullptr);
    }
}

// Round 16
// 681.818 us; speedup vs baseline: 1.0148x; 1.0148x over previous
//
#include <hip/hip_runtime.h>
#include <hip/hip_bf16.h>

#define Nn 20000
#define EREL 60000
#define ETOT 180000
#define NG 64
#define FD 384
#define EPS 1e-5f

typedef unsigned short u16;
typedef unsigned int u32;
typedef __attribute__((ext_vector_type(8))) short s8v;     // 8 bf16 (4 VGPR) MFMA A/B frag
typedef __attribute__((ext_vector_type(4))) float f4v;     // MFMA C/D frag

static inline int cdiv(int a, int b) { return (a + b - 1) / b; }

__device__ inline u16 f2b(float f) {
    __hip_bfloat16 h = __float2bfloat16(f);
    union { __hip_bfloat16 b; u16 u; } c; c.b = h; return c.u;
}
__device__ inline float b2f(u16 u) {
    union { __hip_bfloat16 b; u16 u; } c; c.u = u; return __bfloat162float(c.b);
}

// transpose + split: W[b][K][N] -> T[b][N][K] hi(/lo)
template<bool WLO>
__global__ void tsplit_k(const float* __restrict__ W, u16* __restrict__ hi,
                         u16* __restrict__ lo, int K, int N, int total)
{
    int idx = blockIdx.x * 256 + threadIdx.x;
    if (idx >= total) return;
    int kn = K * N;
    int b = idx / kn, rem = idx - b * kn;
    int k = rem / N, n = rem - k * N;
    float v = W[idx];
    u16 h = f2b(v);
    int o = b * kn + n * K + k;
    hi[o] = h;
    if (WLO) lo[o] = f2b(v - b2f(h));
}

// W2T[L][r*16+c][kin] = sum_d W[L][r][kin][d] * (c<8 ? q[d][c] : k[d][c-8])
__global__ __launch_bounds__(256) void w2_k(const float* __restrict__ W0,
    const float* __restrict__ q0, const float* __restrict__ k0,
    const float* __restrict__ W1, const float* __restrict__ q1, const float* __restrict__ k1,
    u16* __restrict__ hi, u16* __restrict__ lo)
{
    int row = blockIdx.x * 4 + (threadIdx.x >> 6);   // 2304 rows
    int lane = threadIdx.x & 63;
    if (row >= 2304) return;
    int kin = row % 384;
    int lr3 = row / 384;
    int L = lr3 / 3, r = lr3 - L * 3;
    const float* W = (L ? W1 : W0) + ((size_t)r * 384 + kin) * 384;
    const float* qm = L ? q1 : q0;
    const float* km = L ? k1 : k0;
    float pq[16] = {};
    #pragma unroll
    for (int j = 0; j < 6; j++) {
        int d = lane + 64 * j;
        float x = W[d];
        #pragma unroll
        for (int h = 0; h < 8; h++) {
            pq[h]     = fmaf(x, qm[d * 8 + h], pq[h]);
            pq[8 + h] = fmaf(x, km[d * 8 + h], pq[8 + h]);
        }
    }
    #pragma unroll
    for (int o = 32; o; o >>= 1) {
        #pragma unroll
        for (int h = 0; h < 16; h++) pq[h] += __shfl_down(pq[h], o);
    }
    if (lane == 0) {
        #pragma unroll
        for (int c = 0; c < 16; c++) {
            u16 hh = f2b(pq[c]);
            size_t o = ((size_t)L * 48 + r * 16 + c) * 384 + kin;
            hi[o] = hh; lo[o] = f2b(pq[c] - b2f(hh));
        }
    }
}

// ---------------- small-K encoder GEMM ----------------
__global__ __launch_bounds__(256) void enc_gemm_k(const float* __restrict__ x, int K,
    const float* __restrict__ W, const float* __restrict__ bias,
    u16* __restrict__ out, float* __restrict__ stats)
{
    __shared__ float Wl[33 * 128];
    __shared__ float bl[128];
    __shared__ float red[8];
    int t = threadIdx.x;
    for (int i = t; i < K * 128; i += 256) Wl[i] = W[i];
    if (t < 128) bl[t] = bias[t];
    __syncthreads();
    int wid = t >> 6, lane = t & 63;
    float s1 = 0.f, s2 = 0.f;
    for (int rr = 0; rr < 8; rr++) {
        int n = blockIdx.x * 32 + wid * 8 + rr;
        if (n >= Nn) break;
        float xv = (lane < K) ? x[(size_t)n * K + lane] : 0.f;
        float a0 = 0.f, a1 = 0.f;
        for (int k = 0; k < K; k++) {
            float xk = __shfl(xv, k);
            a0 = fmaf(xk, Wl[k * 128 + 2 * lane], a0);
            a1 = fmaf(xk, Wl[k * 128 + 2 * lane + 1], a1);
        }
        a0 = fmaxf(a0 + bl[2 * lane], 0.f);
        a1 = fmaxf(a1 + bl[2 * lane + 1], 0.f);
        ((u32*)(out + (size_t)n * FD))[lane] = (u32)f2b(a0) | ((u32)f2b(a1) << 16);
        s1 += a0 + a1; s2 += a0 * a0 + a1 * a1;
    }
    #pragma unroll
    for (int o = 32; o; o >>= 1) { s1 += __shfl_down(s1, o); s2 += __shfl_down(s2, o); }
    if (lane == 0) { red[wid] = s1; red[4 + wid] = s2; }
    __syncthreads();
    if (t == 0) atomicAdd(&stats[0], red[0] + red[1] + red[2] + red[3]);
    if (t == 1) atomicAdd(&stats[1], red[4] + red[5] + red[6] + red[7]);
}

// ---------------- split-bf16 MFMA GEMM (LDS sized by TERMS) ----------------
#define USEI(i) ((i) < 2 || ((i) >= 4 && (i) < 6) || (TERMS >= 2 && ((i) == 2 || (i) == 3)) || (TERMS >= 3 && (i) >= 6))
template<bool BIAS, bool RELU, bool STATS, bool OB16, int TERMS, bool SWZ, bool AF32>
__global__ __launch_bounds__(256) void mgemm_k(
    const u16* __restrict__ Ahi, const u16* __restrict__ Alo, const float* __restrict__ Af,
    const u16* __restrict__ Bhi, const u16* __restrict__ Blo,
    const float* __restrict__ bias, void* __restrict__ Cv,
    int M, int K, int ldc, int bstride, float* __restrict__ stats)
{
    constexpr int NTILE = (TERMS >= 3) ? 4 : (TERMS + 1);   // 1->2, 2->3, 3->4
    constexpr int tmap[4] = { 0, 1, (TERMS == 1 ? 1 : 2), 3 };
    __shared__ u16 lds[NTILE * 128 * 32];
    __shared__ float red[256];
    const int t = threadIdx.x;
    int brow, bcol, z;
    if (SWZ) {
        int d = blockIdx.x;
        int xcd = d & 7, s = d >> 3;
        int row = xcd + 8 * (s / 9);
        int c = s % 9;
        brow = row * 128;
        if (brow >= M) return;
        bcol = (c % 3) * 128;
        z = c / 3;
    } else {
        brow = blockIdx.x * 128; bcol = blockIdx.y * 128; z = blockIdx.z;
    }
    Bhi += (size_t)z * bstride;
    Blo += (size_t)z * bstride;
    float* Cf = OB16 ? nullptr : (float*)Cv + (size_t)z * M * ldc;
    u16*   Ch = OB16 ? (u16*)Cv + (size_t)z * M * ldc : nullptr;

    const int r0 = t >> 2, sl = t & 3;
    const int rA0 = min(brow + r0, M - 1);
    const int rA1 = min(brow + r0 + 64, M - 1);
    const u16* gsrc[8];
    gsrc[0] = Ahi + (size_t)rA0 * K + sl * 8;
    gsrc[1] = Ahi + (size_t)rA1 * K + sl * 8;
    gsrc[2] = Alo + (size_t)rA0 * K + sl * 8;
    gsrc[3] = Alo + (size_t)rA1 * K + sl * 8;
    gsrc[4] = Bhi + (size_t)(bcol + r0) * K + sl * 8;
    gsrc[5] = Bhi + (size_t)(bcol + r0 + 64) * K + sl * 8;
    gsrc[6] = Blo + (size_t)(bcol + r0) * K + sl * 8;
    gsrc[7] = Blo + (size_t)(bcol + r0 + 64) * K + sl * 8;
    const float* afsrc[2];
    if (AF32) {
        afsrc[0] = Af + (size_t)rA0 * K + sl * 8;
        afsrc[1] = Af + (size_t)rA1 * K + sl * 8;
    }
    const int swz = (sl ^ (r0 & 3)) << 3;
    int ldst[8];
    #pragma unroll
    for (int i = 0; i < 8; i++) {
        int tile = tmap[i >> 1], row = r0 + 64 * (i & 1);
        ldst[i] = tile * 4096 + row * 32 + swz;
    }

    const int l = t & 63, w = t >> 6;
    const int wr = (w >> 1) * 64, wc = (w & 1) * 64;
    const int lr = l & 15, kq = l >> 4;

    f4v acc[4][4] = {};
    const int NK = K >> 5;

    #define LDA32(i, ko) ({ \
        float4 f0_ = *(const float4*)(afsrc[i] + (ko)); \
        float4 f1_ = *(const float4*)(afsrc[i] + (ko) + 4); \
        s8v r_; \
        r_[0] = (short)f2b(f0_.x); r_[1] = (short)f2b(f0_.y); \
        r_[2] = (short)f2b(f0_.z); r_[3] = (short)f2b(f0_.w); \
        r_[4] = (short)f2b(f1_.x); r_[5] = (short)f2b(f1_.y); \
        r_[6] = (short)f2b(f1_.z); r_[7] = (short)f2b(f1_.w); \
        r_; })

    s8v stg[8];
    #pragma unroll
    for (int i = 0; i < 8; i++) {
        if (AF32 && i < 2) stg[i] = LDA32(i, 0);
        else if (!(AF32 && i < 2) && USEI(i)) stg[i] = *(const s8v*)gsrc[i];
    }

    for (int kc = 0; kc < NK; kc++) {
        if (kc) __syncthreads();
        #pragma unroll
        for (int i = 0; i < 8; i++) if (USEI(i)) *(s8v*)(lds + ldst[i]) = stg[i];
        __syncthreads();
        if (kc + 1 < NK) {
            const int ko = (kc + 1) * 32;
            #pragma unroll
            for (int i = 0; i < 8; i++) {
                if (AF32 && i < 2) stg[i] = LDA32(i, ko);
                else if (!(AF32 && i < 2) && USEI(i)) stg[i] = *(const s8v*)(gsrc[i] + ko);
            }
        }
        #define LDR(T, row) (*(const s8v*)(lds + tmap[T] * 4096 + (row) * 32 + ((kq ^ ((row) & 3)) << 3)))
        s8v bh[4], bl[4];
        #pragma unroll
        for (int tn = 0; tn < 4; tn++) {
            int rb = wc + tn * 16 + lr;
            bh[tn] = LDR(2, rb);
            if (TERMS >= 3) bl[tn] = LDR(3, rb);
        }
        #pragma unroll
        for (int tm = 0; tm < 4; tm++) {
            int ra = wr + tm * 16 + lr;
            s8v ah = LDR(0, ra);
            s8v al;
            if (TERMS >= 2) al = LDR(1, ra);
            #pragma unroll
            for (int tn = 0; tn < 4; tn++) {
                acc[tm][tn] = __builtin_amdgcn_mfma_f32_16x16x32_bf16(ah, bh[tn], acc[tm][tn], 0, 0, 0);
                if (TERMS >= 2)
                    acc[tm][tn] = __builtin_amdgcn_mfma_f32_16x16x32_bf16(al, bh[tn], acc[tm][tn], 0, 0, 0);
                if (TERMS >= 3)
                    acc[tm][tn] = __builtin_amdgcn_mfma_f32_16x16x32_bf16(ah, bl[tn], acc[tm][tn], 0, 0, 0);
            }
        }
        #undef LDR
    }
    #undef LDA32

    float s1 = 0.f, s2 = 0.f;
    #pragma unroll
    for (int tm = 0; tm < 4; tm++) {
        #pragma unroll
        for (int rg = 0; rg < 4; rg++) {
            int row = brow + wr + tm * 16 + kq * 4 + rg;
            if (row < M) {
                #pragma unroll
                for (int tn = 0; tn < 4; tn++) {
                    int col = bcol + wc + tn * 16 + lr;
                    float v = acc[tm][tn][rg];
                    if (BIAS) v += bias[col];
                    if (RELU) v = fmaxf(v, 0.f);
                    if (OB16) Ch[(size_t)row * ldc + col] = f2b(v);
                    else      Cf[(size_t)row * ldc + col] = v;
                    if (STATS) { s1 += v; s2 += v * v; }
                }
            }
        }
    }
    if (STATS) {
        __syncthreads();
        red[t] = s1; __syncthreads();
        for (int o = 128; o; o >>= 1) { if (t < o) red[t] += red[t + o]; __syncthreads(); }
        if (t == 0) atomicAdd(&stats[0], red[0]);
        __syncthreads();
        red[t] = s2; __syncthreads();
        for (int o = 128; o; o >>= 1) { if (t < o) red[t] += red[t + o]; __syncthreads(); }
        if (t == 0) atomicAdd(&stats[1], red[0]);
    }
}
#undef USEI

// ---------------- fused classifier ----------------
template<bool DOSM>
__global__ __launch_bounds__(256) void mcls_k(
    const u16* __restrict__ A, const u16* __restrict__ Bh, const float* __restrict__ b1,
    const u16* __restrict__ w2hi, const u16* __restrict__ w2lo, const float* __restrict__ b2,
    float* __restrict__ outp, float* __restrict__ prior)
{
    __shared__ u16 lds[128 * 132];
    __shared__ u16 w2lds[2][32 * 132];
    const int t = threadIdx.x;
    const int brow = blockIdx.x * 128;

    for (int i = t; i < 512; i += 256) {
        int row = i >> 4, c8 = (i & 15) * 8;
        *(s8v*)&w2lds[0][row * 132 + c8] = *(const s8v*)(w2hi + row * 128 + c8);
        *(s8v*)&w2lds[1][row * 132 + c8] = *(const s8v*)(w2lo + row * 128 + c8);
    }

    const int r0 = t >> 2, sl = t & 3;
    const int rA0 = min(brow + r0, Nn - 1);
    const int rA1 = min(brow + r0 + 64, Nn - 1);
    const u16* gA0 = A + (size_t)rA0 * FD + sl * 8;
    const u16* gA1 = A + (size_t)rA1 * FD + sl * 8;
    const u16* gB0 = Bh + (size_t)r0 * FD + sl * 8;
    const u16* gB1 = Bh + (size_t)(r0 + 64) * FD + sl * 8;
    const int swz = (sl ^ (r0 & 3)) << 3;
    const int la0 = r0 * 32 + swz, la1 = (r0 + 64) * 32 + swz;
    const int lb0 = 2 * 4096 + r0 * 32 + swz, lb1 = 2 * 4096 + (r0 + 64) * 32 + swz;

    const int l = t & 63, w = t >> 6;
    const int wr = (w >> 1) * 64, wc = (w & 1) * 64;
    const int lr = l & 15, kq = l >> 4;

    f4v acc[4][4] = {};
    s8v sA0 = *(const s8v*)gA0, sA1 = *(const s8v*)gA1;
    s8v sB0 = *(const s8v*)gB0, sB1 = *(const s8v*)gB1;
    for (int kc = 0; kc < 12; kc++) {
        if (kc) __syncthreads();
        *(s8v*)(lds + la0) = sA0; *(s8v*)(lds + la1) = sA1;
        *(s8v*)(lds + lb0) = sB0; *(s8v*)(lds + lb1) = sB1;
        __syncthreads();
        if (kc + 1 < 12) {
            int ko = (kc + 1) * 32;
            sA0 = *(const s8v*)(gA0 + ko); sA1 = *(const s8v*)(gA1 + ko);
            sB0 = *(const s8v*)(gB0 + ko); sB1 = *(const s8v*)(gB1 + ko);
        }
        #define LDR(T, row) (*(const s8v*)(lds + (T) * 4096 + (row) * 32 + ((kq ^ ((row) & 3)) << 3)))
        s8v bh[4];
        #pragma unroll
        for (int tn = 0; tn < 4; tn++) bh[tn] = LDR(2, wc + tn * 16 + lr);
        #pragma unroll
        for (int tm = 0; tm < 4; tm++) {
            s8v ah = LDR(0, wr + tm * 16 + lr);
            #pragma unroll
            for (int tn = 0; tn < 4; tn++)
                acc[tm][tn] = __builtin_amdgcn_mfma_f32_16x16x32_bf16(ah, bh[tn], acc[tm][tn], 0, 0, 0);
        }
        #undef LDR
    }
    __syncthreads();

    #pragma unroll
    for (int tm = 0; tm < 4; tm++)
        #pragma unroll
        for (int rg = 0; rg < 4; rg++) {
            int row = wr + tm * 16 + kq * 4 + rg;
            #pragma unroll
            for (int tn = 0; tn < 4; tn++) {
                int col = wc + tn * 16 + lr;
                lds[row * 132 + col] = f2b(fmaxf(acc[tm][tn][rg] + b1[col], 0.f));
            }
        }
    __syncthreads();

    f4v a2[2][2] = {};
    #pragma unroll
    for (int ks = 0; ks < 4; ks++) {
        #pragma unroll
        for (int rf = 0; rf < 2; rf++) {
            int ar = w * 32 + rf * 16 + lr;
            s8v av = *(const s8v*)&lds[ar * 132 + ks * 32 + kq * 8];
            #pragma unroll
            for (int cf = 0; cf < 2; cf++) {
                s8v bhv = *(const s8v*)&w2lds[0][(cf * 16 + lr) * 132 + ks * 32 + kq * 8];
                s8v blv = *(const s8v*)&w2lds[1][(cf * 16 + lr) * 132 + ks * 32 + kq * 8];
                a2[rf][cf] = __builtin_amdgcn_mfma_f32_16x16x32_bf16(av, bhv, a2[rf][cf], 0, 0, 0);
                a2[rf][cf] = __builtin_amdgcn_mfma_f32_16x16x32_bf16(av, blv, a2[rf][cf], 0, 0, 0);
            }
        }
    }
    #pragma unroll
    for (int rf = 0; rf < 2; rf++) {
        #pragma unroll
        for (int rg = 0; rg < 4; rg++) {
            int grow = brow + w * 32 + rf * 16 + kq * 4 + rg;
            float v0 = a2[rf][0][rg] + b2[lr];
            float v1 = a2[rf][1][rg] + b2[16 + lr];
            if (grow < Nn) {
                outp[(size_t)grow * 32 + lr] = v0;
                outp[(size_t)grow * 32 + 16 + lr] = v1;
            }
            if (DOSM) {
                float m = fmaxf(v0, v1);
                m = fmaxf(m, __shfl_xor(m, 1));
                m = fmaxf(m, __shfl_xor(m, 2));
                m = fmaxf(m, __shfl_xor(m, 4));
                m = fmaxf(m, __shfl_xor(m, 8));
                float e0 = __expf(v0 - m), e1 = __expf(v1 - m);
                float s = e0 + e1;
                s += __shfl_xor(s, 1); s += __shfl_xor(s, 2);
                s += __shfl_xor(s, 4); s += __shfl_xor(s, 8);
                if (grow < Nn) {
                    float rs = 1.f / s;
                    prior[(size_t)grow * 33 + lr] = e0 * rs;
                    prior[(size_t)grow * 33 + 16 + lr] = e1 * rs;
                    if (lr == 0) prior[(size_t)grow * 33 + 32] = rs;
                }
            }
        }
    }
}

// ---------------- projh GEMM: QIK[Nn,48] = HS(bf16) @ W2T[48,384]^T ----------------
__global__ __launch_bounds__(256) void projh_k(const u16* __restrict__ hs,
    const u16* __restrict__ w2hi, const u16* __restrict__ w2lo, float* __restrict__ qik)
{
    __shared__ u16 a_lds[128 * 32];
    __shared__ u16 b_lds[2][48 * 392];
    int t = threadIdx.x;
    int brow = blockIdx.x * 128;

    for (int i = t; i < 2304; i += 256) {
        int col = i / 48, c8 = (i - col * 48) * 8;
        *(s8v*)&b_lds[0][col * 392 + c8] = *(const s8v*)(w2hi + col * 384 + c8);
        *(s8v*)&b_lds[1][col * 392 + c8] = *(const s8v*)(w2lo + col * 384 + c8);
    }

    int ar = t >> 1, sl0 = (t & 1) * 2;
    int grow = min(brow + ar, Nn - 1);
    const u16* asrc = hs + (size_t)grow * FD;
    int adst0 = ar * 32 + ((sl0 ^ (ar & 3)) << 3);
    int adst1 = ar * 32 + (((sl0 + 1) ^ (ar & 3)) << 3);

    int l = t & 63, w = t >> 6;
    int lr = l & 15, kq = l >> 4;
    f4v acc[2][3] = {};

    s8v stg0 = *(const s8v*)(asrc + sl0 * 8);
    s8v stg1 = *(const s8v*)(asrc + sl0 * 8 + 8);
    for (int kc = 0; kc < 12; kc++) {
        if (kc) __syncthreads();
        *(s8v*)&a_lds[adst0] = stg0;
        *(s8v*)&a_lds[adst1] = stg1;
        __syncthreads();
        if (kc + 1 < 12) {
            int ko = (kc + 1) * 32 + sl0 * 8;
            stg0 = *(const s8v*)(asrc + ko);
            stg1 = *(const s8v*)(asrc + ko + 8);
        }
        s8v bh[3], bl[3];
        #pragma unroll
        for (int cf = 0; cf < 3; cf++) {
            bh[cf] = *(const s8v*)&b_lds[0][(cf * 16 + lr) * 392 + kc * 32 + kq * 8];
            bl[cf] = *(const s8v*)&b_lds[1][(cf * 16 + lr) * 392 + kc * 32 + kq * 8];
        }
        #pragma unroll
        for (int rf = 0; rf < 2; rf++) {
            int rr = w * 32 + rf * 16 + lr;
            s8v a = *(const s8v*)&a_lds[rr * 32 + ((kq ^ (rr & 3)) << 3)];
            #pragma unroll
            for (int cf = 0; cf < 3; cf++) {
                acc[rf][cf] = __builtin_amdgcn_mfma_f32_16x16x32_bf16(a, bh[cf], acc[rf][cf], 0, 0, 0);
                acc[rf][cf] = __builtin_amdgcn_mfma_f32_16x16x32_bf16(a, bl[cf], acc[rf][cf], 0, 0, 0);
            }
        }
    }
    #pragma unroll
    for (int rf = 0; rf < 2; rf++)
        #pragma unroll
        for (int cf = 0; cf < 3; cf++)
            #pragma unroll
            for (int rg = 0; rg < 4; rg++) {
                int row = brow + w * 32 + rf * 16 + kq * 4 + rg;
                if (row < Nn) qik[(size_t)row * 48 + cf * 16 + lr] = acc[rf][cf][rg];
            }
}

// scalar-LN of a 128-col block (bf16 pre-norm, pre-offset) from RAW sums -> bf16 hi
__global__ __launch_bounds__(256) void enc_norm_k(const u16* __restrict__ H,
                           const float* __restrict__ w, const float* __restrict__ b,
                           const float* __restrict__ stats, float cntinv, u16* __restrict__ hi)
{
    int i = blockIdx.x * 256 + threadIdx.x;
    if (i >= Nn * 32) return;
    int n = i >> 5, c4 = i & 31;
    float m = stats[0] * cntinv;
    float var = stats[1] * cntinv - m * m;
    float s = 1.f / (sqrtf(fmaxf(var, 0.f)) + EPS);
    float4 wv = ((const float4*)w)[c4];
    float4 bv = ((const float4*)b)[c4];
    uint2 yv = ((const uint2*)(H + (size_t)n * FD))[c4];
    ushort4 hh;
    hh.x = f2b((b2f((u16)(yv.x & 0xffffu)) - m) * s * wv.x + bv.x);
    hh.y = f2b((b2f((u16)(yv.x >> 16))     - m) * s * wv.y + bv.y);
    hh.z = f2b((b2f((u16)(yv.y & 0xffffu)) - m) * s * wv.z + bv.z);
    hh.w = f2b((b2f((u16)(yv.y >> 16))     - m) * s * wv.w + bv.w);
    ((ushort4*)(hi + (size_t)n * FD))[c4] = hh;
}

__global__ void edge_count_k(const int* __restrict__ e0, const int* __restrict__ e1,
                             const int* __restrict__ e2, int* __restrict__ cnt)
{
    int e = blockIdx.x * 256 + threadIdx.x;
    if (e >= ETOT) return;
    int r = e / EREL, i = e - r * EREL;
    const int* ei = (r == 0) ? e0 : (r == 1) ? e1 : e2;
    atomicAdd(&cnt[ei[EREL + i]], 1);
}

__global__ void edge_fill_k(const int* __restrict__ e0, const int* __restrict__ e1,
                            const int* __restrict__ e2, int* __restrict__ cursor,
                            int* __restrict__ eidx)
{
    int e = blockIdx.x * 256 + threadIdx.x;
    if (e >= ETOT) return;
    int r = e / EREL, i = e - r * EREL;
    const int* ei = (r == 0) ? e0 : (r == 1) ? e1 : e2;
    int src = ei[i], dst = ei[EREL + i];
    int pos = atomicAdd(&cursor[dst], 1);
    eidx[pos] = src | (r << 24);
}

// exclusive scan via per-wave shuffle scan + 16-wave LDS combine
__global__ __launch_bounds__(1024) void scan_k(const int* __restrict__ cnt,
                                               int* __restrict__ rowptr, int* __restrict__ cursor)
{
    __shared__ int wsum[16], wpre[16];
    __shared__ int carry, tot;
    int t = threadIdx.x, lane = t & 63, wid = t >> 6;
    if (t == 0) carry = 0;
    __syncthreads();
    for (int base = 0; base < Nn; base += 1024) {
        int i = base + t;
        int v = (i < Nn) ? cnt[i] : 0;
        int s = v;
        #pragma unroll
        for (int o = 1; o < 64; o <<= 1) {
            int x = __shfl_up(s, o);
            if (lane >= o) s += x;
        }
        if (lane == 63) wsum[wid] = s;
        __syncthreads();
        if (t < 16) {
            int wv = wsum[t];
            int ws = wv;
            #pragma unroll
            for (int o = 1; o < 16; o <<= 1) {
                int x = __shfl_up(ws, o);
                if (t >= o) ws += x;
            }
            wpre[t] = ws - wv;
            if (t == 15) tot = ws;
        }
        __syncthreads();
        if (i < Nn) {
            int ex = carry + wpre[wid] + s - v;
            rowptr[i] = ex; cursor[i] = ex;
        }
        __syncthreads();
        if (t == 0) carry += tot;
    }
    __syncthreads();
    if (t == 0) rowptr[Nn] = carry;
}

// per-graph node counts via LDS histogram
__global__ __launch_bounds__(256) void gcount_k(const int* __restrict__ batch, int* __restrict__ gcnt)
{
    __shared__ int bins[NG];
    int t = threadIdx.x;
    if (t < NG) bins[t] = 0;
    __syncthreads();
    int n = blockIdx.x * 256 + t;
    if (n < Nn) atomicAdd(&bins[batch[n]], 1);
    __syncthreads();
    if (t < NG && bins[t]) atomicAdd(&gcnt[t], bins[t]);
}

// RGAT aggregation, softmax fused. One wave per node, 4x edge unroll, dwordx3 gather.
__global__ __launch_bounds__(256) void aggr_k(const u16* __restrict__ xr,
    const float* __restrict__ qik, const int* __restrict__ rowptr, const int* __restrict__ eidx,
    const float* __restrict__ bias, const u16* __restrict__ hinb,
    const int* __restrict__ batch, u16* __restrict__ outb,
    float* __restrict__ gsum, float* __restrict__ gsq)
{
    __shared__ float ls[NG], lq[NG];
    int t = threadIdx.x;
    if (t < NG) { ls[t] = 0.f; lq[t] = 0.f; }
    __syncthreads();
    int node = blockIdx.x * 4 + (t >> 6);
    int lane = t & 63;
    int e0 = rowptr[node], e1 = rowptr[node + 1];
    int hd = lane >> 3;
    float qv = (lane < 48) ? qik[(size_t)node * 48 + lane] : 0.f;
    float den = 0.f;
    float acc[6] = {};

    int e = e0;
    while (e + 4 <= e1) {
        int p0 = eidx[e], p1 = eidx[e + 1], p2 = eidx[e + 2], p3 = eidx[e + 3];
        int n0 = p0 & 0xFFFFFF, et0 = p0 >> 24;
        int n1 = p1 & 0xFFFFFF, et1 = p1 >> 24;
        int n2 = p2 & 0xFFFFFF, et2 = p2 >> 24;
        int n3 = p3 & 0xFFFFFF, et3 = p3 >> 24;
        float kv0 = (lane < 8) ? qik[(size_t)n0 * 48 + et0 * 16 + 8 + lane] : 0.f;
        float kv1 = (lane < 8) ? qik[(size_t)n1 * 48 + et1 * 16 + 8 + lane] : 0.f;
        float kv2 = (lane < 8) ? qik[(size_t)n2 * 48 + et2 * 16 + 8 + lane] : 0.f;
        float kv3 = (lane < 8) ? qik[(size_t)n3 * 48 + et3 * 16 + 8 + lane] : 0.f;
        const u32* r0 = (const u32*)(xr + ((size_t)et0 * Nn + n0) * FD);
        const u32* r1 = (const u32*)(xr + ((size_t)et1 * Nn + n1) * FD);
        const u32* r2 = (const u32*)(xr + ((size_t)et2 * Nn + n2) * FD);
        const u32* r3 = (const u32*)(xr + ((size_t)et3 * Nn + n3) * FD);
        u32 u0[3], u1[3], u2[3], u3[3];
        #pragma unroll
        for (int j = 0; j < 3; j++) u0[j] = r0[lane * 3 + j];
        #pragma unroll
        for (int j = 0; j < 3; j++) u1[j] = r1[lane * 3 + j];
        #pragma unroll
        for (int j = 0; j < 3; j++) u2[j] = r2[lane * 3 + j];
        #pragma unroll
        for (int j = 0; j < 3; j++) u3[j] = r3[lane * 3 + j];
        float qq0 = __shfl(qv, et0 * 16 + (lane & 7));
        float qq1 = __shfl(qv, et1 * 16 + (lane & 7));
        float qq2 = __shfl(qv, et2 * 16 + (lane & 7));
        float qq3 = __shfl(qv, et3 * 16 + (lane & 7));
        float ex0 = 0.f, ex1 = 0.f, ex2 = 0.f, ex3 = 0.f;
        if (lane < 8) {
            float a0 = qq0 + kv0; a0 = (a0 > 0.f) ? a0 : 0.2f * a0; ex0 = __expf(a0);
            float a1 = qq1 + kv1; a1 = (a1 > 0.f) ? a1 : 0.2f * a1; ex1 = __expf(a1);
            float a2 = qq2 + kv2; a2 = (a2 > 0.f) ? a2 : 0.2f * a2; ex2 = __expf(a2);
            float a3 = qq3 + kv3; a3 = (a3 > 0.f) ? a3 : 0.2f * a3; ex3 = __expf(a3);
        }
        den += ex0 + ex1 + ex2 + ex3;
        float w0 = __shfl(ex0, hd), w1 = __shfl(ex1, hd);
        float w2 = __shfl(ex2, hd), w3 = __shfl(ex3, hd);
        #pragma unroll
        for (int j = 0; j < 3; j++) {
            acc[2*j]   = fmaf(w0, __uint_as_float(u0[j] << 16), acc[2*j]);
            acc[2*j+1] = fmaf(w0, __uint_as_float(u0[j] & 0xffff0000u), acc[2*j+1]);
            acc[2*j]   = fmaf(w1, __uint_as_float(u1[j] << 16), acc[2*j]);
            acc[2*j+1] = fmaf(w1, __uint_as_float(u1[j] & 0xffff0000u), acc[2*j+1]);
            acc[2*j]   = fmaf(w2, __uint_as_float(u2[j] << 16), acc[2*j]);
            acc[2*j+1] = fmaf(w2, __uint_as_float(u2[j] & 0xffff0000u), acc[2*j+1]);
            acc[2*j]   = fmaf(w3, __uint_as_float(u3[j] << 16), acc[2*j]);
            acc[2*j+1] = fmaf(w3, __uint_as_float(u3[j] & 0xffff0000u), acc[2*j+1]);
        }
        e += 4;
    }
    for (; e < e1; e++) {
        int p = eidx[e];
        int sn = p & 0xFFFFFF, et = p >> 24;
        float kv = (lane < 8) ? qik[(size_t)sn * 48 + et * 16 + 8 + lane] : 0.f;
        const u32* rr = (const u32*)(xr + ((size_t)et * Nn + sn) * FD);
        u32 u[3];
        #pragma unroll
        for (int j = 0; j < 3; j++) u[j] = rr[lane * 3 + j];
        float qq = __shfl(qv, et * 16 + (lane & 7));
        float ex = 0.f;
        if (lane < 8) { float a = qq + kv; a = (a > 0.f) ? a : 0.2f * a; ex = __expf(a); }
        den += ex;
        float wv_ = __shfl(ex, hd);
        #pragma unroll
        for (int j = 0; j < 3; j++) {
            acc[2*j]   = fmaf(wv_, __uint_as_float(u[j] << 16), acc[2*j]);
            acc[2*j+1] = fmaf(wv_, __uint_as_float(u[j] & 0xffff0000u), acc[2*j+1]);
        }
    }

    float dh = __shfl(den, hd);
    float rcp = 1.f / (dh + 1e-16f);
    const u32* hp = (const u32*)(hinb + (size_t)node * FD);
    u32* op = (u32*)(outb + (size_t)node * FD);
    float s1 = 0.f, s2 = 0.f;
    #pragma unroll
    for (int j = 0; j < 3; j++) {
        int c = lane * 6 + 2 * j;
        float2 bv = *(const float2*)(bias + c);
        u32 hb = hp[lane * 3 + j];
        float vx = acc[2*j] * rcp + bv.x;
        float vy = acc[2*j+1] * rcp + bv.y;
        vx = (vx > 0.f) ? vx : expm1f(vx);
        vy = (vy > 0.f) ? vy : expm1f(vy);
        vx += b2f((u16)(hb & 0xffffu));
        vy += b2f((u16)(hb >> 16));
        op[lane * 3 + j] = (u32)f2b(vx) | ((u32)f2b(vy) << 16);
        s1 += vx + vy; s2 += vx * vx + vy * vy;
    }
    #pragma unroll
    for (int o = 32; o; o >>= 1) { s1 += __shfl_down(s1, o); s2 += __shfl_down(s2, o); }
    int g = batch[node];
    if (lane == 0) { atomicAdd(&ls[g], s1); atomicAdd(&lq[g], s2); }
    __syncthreads();
    if (t < NG && (ls[t] != 0.f || lq[t] != 0.f)) {
        atomicAdd(&gsum[t], ls[t]);
        atomicAdd(&gsq[t], lq[t]);
    }
}

// graph-LN from raw sums, bf16 input -> bf16 hi
__global__ __launch_bounds__(256) void gnorm_split_k(const u16* __restrict__ yb,
    const int* __restrict__ batch, const float* __restrict__ gsum, const float* __restrict__ gsq,
    const int* __restrict__ gcnt, const float* __restrict__ w, const float* __restrict__ b,
    u16* __restrict__ hi)
{
    int i = blockIdx.x * 256 + threadIdx.x;
    if (i >= Nn * (FD / 4)) return;
    int n = i / 96;
    int c4 = i - n * 96;
    int g = batch[n];
    float norm = fmaxf((float)gcnt[g], 1.f) * (float)FD;
    float m = gsum[g] / norm;
    float var = gsq[g] / norm - m * m;
    float rstd = rsqrtf(var + EPS);
    float4 wv = ((const float4*)w)[c4];
    float4 bv = ((const float4*)b)[c4];
    uint2 yv = ((const uint2*)yb)[i];
    ushort4 hh;
    hh.x = f2b((b2f((u16)(yv.x & 0xffffu)) - m) * rstd * wv.x + bv.x);
    hh.y = f2b((b2f((u16)(yv.x >> 16))     - m) * rstd * wv.y + bv.y);
    hh.z = f2b((b2f((u16)(yv.y & 0xffffu)) - m) * rstd * wv.z + bv.z);
    hh.w = f2b((b2f((u16)(yv.y >> 16))     - m) * rstd * wv.w + bv.w);
    ((ushort4*)hi)[i] = hh;
}

extern "C" void kernel_launch(void* const* d_in, const int* in_sizes, int n_in,
                              void* d_out, int out_size, void* d_ws, size_t ws_size,
                              hipStream_t stream)
{
    const float* x_visual = (const float*)d_in[0];
    const float* x_geom   = (const float*)d_in[1];
    const float* x_prior  = (const float*)d_in[2];
    const int* ei0   = (const int*)d_in[3];
    const int* ei1   = (const int*)d_in[4];
    const int* ei2   = (const int*)d_in[5];
    const int* batch = (const int*)d_in[6];
    const float* vis_W = (const float*)d_in[7];  const float* vis_b = (const float*)d_in[8];
    const float* vis_lnw = (const float*)d_in[9]; const float* vis_lnb = (const float*)d_in[10];
    const float* geo_W = (const float*)d_in[11]; const float* geo_b = (const float*)d_in[12];
    const float* geo_lnw = (const float*)d_in[13]; const float* geo_lnb = (const float*)d_in[14];
    const float* pri_W = (const float*)d_in[15]; const float* pri_b = (const float*)d_in[16];
    const float* pri_lnw = (const float*)d_in[17]; const float* pri_lnb = (const float*)d_in[18];
    const float* rgat_W[2]    = { (const float*)d_in[19], (const float*)d_in[25] };
    const float* rgat_q[2]    = { (const float*)d_in[20], (const float*)d_in[26] };
    const float* rgat_kk[2]   = { (const float*)d_in[21], (const float*)d_in[27] };
    const float* rgat_bias[2] = { (const float*)d_in[22], (const float*)d_in[28] };
    const float* ln_w[2]      = { (const float*)d_in[23], (const float*)d_in[29] };
    const float* ln_b[2]      = { (const float*)d_in[24], (const float*)d_in[30] };
    const float* cls_W1 = (const float*)d_in[31]; const float* cls_b1 = (const float*)d_in[32];
    const float* cls_W2 = (const float*)d_in[33]; const float* cls_b2 = (const float*)d_in[34];
    float* OUT = (float*)d_out;

    // ---------------- workspace layout ----------------
    float* ws = (float*)d_ws;
    float* XRreg = ws;
    u16*   XR16  = (u16*)XRreg;
    float* HCAT  = XRreg + (size_t)3 * Nn * FD;
    u16*   HENC  = (u16*)HCAT;
    float* HA    = HCAT + (size_t)Nn * FD;
    float* HB    = HA + (size_t)Nn * FD;
    float* PRIOR = HB + (size_t)Nn * FD;
    float* QIK   = PRIOR + (size_t)Nn * 33;
    u16* HS0_HI  = (u16*)(QIK + (size_t)Nn * 48);
    u16* HS0_LO  = HS0_HI + (size_t)Nn * FD;
    u16* HS1_HI  = HS0_LO + (size_t)Nn * FD;
    u16* HS1_LO  = HS1_HI + (size_t)Nn * FD;
    u16* RW_HI   = HS1_LO + (size_t)Nn * FD;
    u16* RW_LO   = RW_HI + (size_t)2 * 3 * 384 * 384;
    u16* VW_HI   = RW_LO + (size_t)2 * 3 * 384 * 384;
    u16* VW_LO   = VW_HI + (size_t)128 * 1024;
    u16* CW_HI   = VW_LO + (size_t)128 * 1024;
    u16* W2T_HI  = CW_HI + (size_t)128 * 384;
    u16* W2T_LO  = W2T_HI + (size_t)32 * 128;
    u16* W2_HI   = W2T_LO + (size_t)32 * 128;
    u16* W2_LO   = W2_HI + (size_t)2 * 48 * 384;
    float* GS    = (float*)(W2_LO + (size_t)2 * 48 * 384);
    float* STATS = GS + 512;
    int* CNT    = (int*)(STATS + 8);
    int* ROWPTR = CNT + Nn;
    int* CURSOR = ROWPTR + Nn + 1;
    int* EIDX   = CURSOR + Nn;
    int* GCNT   = EIDX + ETOT;
    u16* HS2_HI = (u16*)(XRreg + (size_t)12 * 1000 * 1000);
    u16* YB0 = (u16*)HA;
    u16* YB1 = (u16*)HB;

    // ---------------- CSR build ----------------
    hipMemsetAsync(CNT, 0, Nn * sizeof(int), stream);
    edge_count_k<<<cdiv(ETOT, 256), 256, 0, stream>>>(ei0, ei1, ei2, CNT);
    scan_k<<<1, 1024, 0, stream>>>(CNT, ROWPTR, CURSOR);
    edge_fill_k<<<cdiv(ETOT, 256), 256, 0, stream>>>(ei0, ei1, ei2, CURSOR, EIDX);
    hipMemsetAsync(GCNT, 0, 64 * sizeof(int), stream);
    gcount_k<<<cdiv(Nn, 256), 256, 0, stream>>>(batch, GCNT);
    hipMemsetAsync(GS, 0, 520 * sizeof(float), stream);

    // ---------------- weight conversions ----------------
    tsplit_k<false><<<cdiv(3 * 384 * 384, 256), 256, 0, stream>>>(rgat_W[0], RW_HI, RW_LO, 384, 384, 3 * 384 * 384);
    tsplit_k<false><<<cdiv(3 * 384 * 384, 256), 256, 0, stream>>>(rgat_W[1], RW_HI + 3 * 384 * 384, RW_LO, 384, 384, 3 * 384 * 384);
    tsplit_k<false><<<cdiv(1024 * 128, 256), 256, 0, stream>>>(vis_W, VW_HI, VW_LO, 1024, 128, 1024 * 128);
    tsplit_k<false><<<cdiv(384 * 128, 256), 256, 0, stream>>>(cls_W1, CW_HI, nullptr, 384, 128, 384 * 128);
    tsplit_k<true><<<cdiv(128 * 32, 256), 256, 0, stream>>>(cls_W2, W2T_HI, W2T_LO, 128, 32, 128 * 32);
    w2_k<<<576, 256, 0, stream>>>(rgat_W[0], rgat_q[0], rgat_kk[0],
                                  rgat_W[1], rgat_q[1], rgat_kk[1], W2_HI, W2_LO);

    const int MB = cdiv(Nn, 128);   // 157
    const int XRBLK = 160 * 9;      // XCD-swizzled
    const float cinv = 1.f / ((float)Nn * 128.f);

    // ---------------- vis encoder ----------------
    mgemm_k<true, true, true, true, 1, false, true><<<dim3(MB, 1, 1), 256, 0, stream>>>(
        nullptr, nullptr, x_visual, VW_HI, VW_LO, vis_b, HENC, Nn, 1024, FD, 0, STATS + 0);
    enc_norm_k<<<cdiv(Nn * 32, 256), 256, 0, stream>>>(HENC, vis_lnw, vis_lnb, STATS + 0, cinv, HS0_HI);

    // ---------------- geo encoder ----------------
    enc_gemm_k<<<cdiv(Nn, 32), 256, 0, stream>>>(x_geom, 6, geo_W, geo_b, HENC + 128, STATS + 2);
    enc_norm_k<<<cdiv(Nn * 32, 256), 256, 0, stream>>>(HENC + 128, geo_lnw, geo_lnb, STATS + 2, cinv, HS0_HI + 128);

    for (int t = 0; t < 2; t++) {
        const float* pin = t ? PRIOR : x_prior;
        enc_gemm_k<<<cdiv(Nn, 32), 256, 0, stream>>>(pin, 33, pri_W, pri_b, HENC + 256, STATS + 4 + 2 * t);
        enc_norm_k<<<cdiv(Nn * 32, 256), 256, 0, stream>>>(HENC + 256, pri_lnw, pri_lnb, STATS + 4 + 2 * t, cinv, HS0_HI + 256);

        for (int L = 0; L < 2; L++) {
            const u16* ahi = L ? HS1_HI : HS0_HI;
            u16* yout = L ? YB1 : YB0;
            u16* snorm = L ? HS2_HI : HS1_HI;
            float* gsum = GS + (t * 2 + L) * 128;
            mgemm_k<false, false, false, true, 1, true, false><<<dim3(XRBLK, 1, 1), 256, 0, stream>>>(
                ahi, ahi, nullptr, RW_HI + (size_t)L * 3 * 384 * 384, RW_LO,
                nullptr, XR16, Nn, 384, FD, 384 * 384, nullptr);
            projh_k<<<MB, 256, 0, stream>>>(ahi,
                W2_HI + (size_t)L * 48 * 384, W2_LO + (size_t)L * 48 * 384, QIK);
            aggr_k<<<cdiv(Nn, 4), 256, 0, stream>>>(XR16, QIK, ROWPTR, EIDX, rgat_bias[L],
                                                    ahi, batch, yout, gsum, gsum + 64);
            gnorm_split_k<<<cdiv(Nn * 96, 256), 256, 0, stream>>>(
                yout, batch, gsum, gsum + 64, GCNT, ln_w[L], ln_b[L], snorm);
        }

        if (t == 0)
            mcls_k<true><<<dim3(MB, 1, 1), 256, 0, stream>>>(
                HS2_HI, CW_HI, cls_b1, W2T_HI, W2T_LO, cls_b2, OUT, PRIOR);
        else
            mcls_k<false><<<dim3(MB, 1, 1), 256, 0, stream>>>(
                HS2_HI, CW_HI, cls_b1, W2T_HI, W2T_LO, cls_b2, OUT, nullptr);
    }
}